// Round 3
// baseline (683.990 us; speedup 1.0000x reference)
//
#include <hip/hip_runtime.h>
#include <hip/hip_bf16.h>
#include <math.h>

// Problem constants (fixed by the reference)
#define NN 8192     // nodes
#define FF 16       // node features
#define HH 64       // hidden
#define GG 256      // graphs
#define LN_EPS 1e-3f
#define BK 256               // k-slice per LDS stage (fp32)
#define KSTAGES (NN / BK)    // 32

typedef __bf16 bf16x8 __attribute__((ext_vector_type(8)));
typedef float  floatx4 __attribute__((ext_vector_type(4)));

// ---------------------------------------------------------------------------
// K1: Zt0 = (X @ W0)^T  (bf16, [64][8192]); LDS-staged, coalesced.
// Also z = log1p(relu(X[:,0])), segment-max of z via uint atomicMax (z >= 0).
// grid 128 x 256 (64 nodes per block)
__global__ __launch_bounds__(256)
void k1_xw0(const float* __restrict__ X,
            const float* __restrict__ W0,
            const int* __restrict__ I,
            __hip_bfloat16* __restrict__ Zt0,
            float* __restrict__ zarr,
            unsigned int* __restrict__ zmax_bits) {
    __shared__ float Xs[64][17];   // +1 pad
    __shared__ float W0s[16][64];
    const int t  = threadIdx.x;
    const int i0 = blockIdx.x * 64;
    {   // stage X tile (64x16) -- one float4 per thread, coalesced
        const int r = t >> 2, c = (t & 3) * 4;
        const float4 v = *reinterpret_cast<const float4*>(&X[(size_t)(i0 + r) * FF + c]);
        Xs[r][c + 0] = v.x; Xs[r][c + 1] = v.y; Xs[r][c + 2] = v.z; Xs[r][c + 3] = v.w;
        // stage W0 (16x64) -- one float4 per thread, coalesced
        const float4 w = *reinterpret_cast<const float4*>(&W0[t * 4]);
        const int wr = t >> 4, wc = (t & 15) * 4;
        W0s[wr][wc + 0] = w.x; W0s[wr][wc + 1] = w.y; W0s[wr][wc + 2] = w.z; W0s[wr][wc + 3] = w.w;
    }
    __syncthreads();
    const int i  = t & 63;          // node within tile
    const int n0 = (t >> 6) * 16;   // 16 output cols per thread
    float s[16];
#pragma unroll
    for (int j = 0; j < 16; ++j) s[j] = 0.f;
#pragma unroll
    for (int m = 0; m < FF; ++m) {
        const float hv = Xs[i][m];
        const float4* wrow = reinterpret_cast<const float4*>(&W0s[m][n0]);
        const float4 w0 = wrow[0], w1 = wrow[1], w2 = wrow[2], w3 = wrow[3];
        s[0]  += hv * w0.x; s[1]  += hv * w0.y; s[2]  += hv * w0.z; s[3]  += hv * w0.w;
        s[4]  += hv * w1.x; s[5]  += hv * w1.y; s[6]  += hv * w1.z; s[7]  += hv * w1.w;
        s[8]  += hv * w2.x; s[9]  += hv * w2.y; s[10] += hv * w2.z; s[11] += hv * w2.w;
        s[12] += hv * w3.x; s[13] += hv * w3.y; s[14] += hv * w3.z; s[15] += hv * w3.w;
    }
#pragma unroll
    for (int j = 0; j < 16; ++j)
        Zt0[(size_t)(n0 + j) * NN + i0 + i] = __float2bfloat16(s[j]);  // 128B coalesced

    if (t < 64) {
        const float z = log1pf(fmaxf(Xs[t][0], 0.f));
        zarr[i0 + t] = z;
        atomicMax(&zmax_bits[I[i0 + t]], __float_as_uint(z));
    }
}

// ---------------------------------------------------------------------------
// LDS-staged streaming GEMM: C = A[8192,8192](fp32->bf16) @ Z (Zt bf16 [64][8192])
// grid 512 x 256 (4 waves): block = 16 rows x full-K accumulate; no k-split.
// A staged in LDS double-buffer [2][16][256] fp32 (16KB each); each wave-level
// staging load is one contiguous 1KB row-run; loads issued BEFORE compute so
// HBM latency hides under MFMA and in-flight bytes are not VGPR-bound.
// XOR swizzle ((row&7)<<2 on float idx) both sides -> ds_read 2-way (free).
// Wave w computes cols w*16..+15 for all 16 rows.
__global__ __launch_bounds__(256)
void k_gemm_lds(const float* __restrict__ A,
                const __hip_bfloat16* __restrict__ Zt,
                float* __restrict__ C) {
    __shared__ float Ab[2][16][256];   // 32 KB
    const int t    = threadIdx.x;
    const int w    = t >> 6;
    const int lane = t & 63;
    const int l16  = lane & 15;
    const int quad = lane >> 4;
    const int row0 = blockIdx.x * 16;
    const int sc   = lane * 4;              // staging col (floats) within row
    const int swz  = (l16 & 7) << 2;        // read-side XOR (float idx)

    // B operand: lane l16 -> Zt col (w*16+l16); quad -> k-octet
    const __hip_bfloat16* bp = Zt + (size_t)(w * 16 + l16) * NN + quad * 8;
    const float* arow = A + (size_t)row0 * NN;

    floatx4 acc = {0.f, 0.f, 0.f, 0.f};

    // prologue: stage 0 into buffer 0
    {
        float4 st[4];
#pragma unroll
        for (int j = 0; j < 4; ++j)
            st[j] = *reinterpret_cast<const float4*>(arow + (size_t)(j * 4 + w) * NN + sc);
#pragma unroll
        for (int j = 0; j < 4; ++j) {
            const int r = j * 4 + w;
            *reinterpret_cast<float4*>(&Ab[0][r][sc ^ ((r & 7) << 2)]) = st[j];
        }
    }
    __syncthreads();

    int cur = 0;
    for (int s = 0; s < KSTAGES; ++s) {
        // issue next stage's global loads FIRST (latency hides under compute)
        float4 nx[4];
        const bool pf = (s + 1 < KSTAGES);
        if (pf) {
#pragma unroll
            for (int j = 0; j < 4; ++j)
                nx[j] = *reinterpret_cast<const float4*>(
                    arow + (size_t)(j * 4 + w) * NN + (size_t)(s + 1) * BK + sc);
        }
        // compute on Ab[cur] (k = s*BK .. +BK-1)
#pragma unroll
        for (int kk = 0; kk < 8; ++kk) {
            const int c = kk * 32 + quad * 8;
            const float4 alo = *reinterpret_cast<const float4*>(&Ab[cur][l16][(c    ) ^ swz]);
            const float4 ahi = *reinterpret_cast<const float4*>(&Ab[cur][l16][(c + 4) ^ swz]);
            bf16x8 af;
            af[0]=(__bf16)alo.x; af[1]=(__bf16)alo.y; af[2]=(__bf16)alo.z; af[3]=(__bf16)alo.w;
            af[4]=(__bf16)ahi.x; af[5]=(__bf16)ahi.y; af[6]=(__bf16)ahi.z; af[7]=(__bf16)ahi.w;
            const bf16x8 b = *reinterpret_cast<const bf16x8*>(bp + (size_t)s * BK + kk * 32);
            acc = __builtin_amdgcn_mfma_f32_16x16x32_bf16(af, b, acc, 0, 0, 0);
        }
        // write next stage into the other buffer, then barrier
        if (pf) {
#pragma unroll
            for (int j = 0; j < 4; ++j) {
                const int r = j * 4 + w;
                *reinterpret_cast<float4*>(&Ab[cur ^ 1][r][sc ^ ((r & 7) << 2)]) = nx[j];
            }
        }
        __syncthreads();
        cur ^= 1;
    }

    // C/D layout: m = quad*4 + reg, n = l16 (HW-verified m89/m91)
#pragma unroll
    for (int r = 0; r < 4; ++r)
        C[(size_t)(row0 + quad * 4 + r) * HH + w * 16 + l16] = acc[r];
}

// ---------------------------------------------------------------------------
// LN epilogue: out = LayerNorm(relu(C + bias)) * gamma + beta (+ resid)
// block 256 -> 16 rows; grid 512
__global__ __launch_bounds__(256)
void k_ln(const float* __restrict__ C,
          const float* __restrict__ bias,
          const float* __restrict__ gamma,
          const float* __restrict__ beta,
          const float* __restrict__ resid,   // nullptr for layer 0
          float* __restrict__ out) {
    const int tid = threadIdx.x;
    const int row = tid >> 4;
    const int c0  = (tid & 15) * 4;
    const size_t grow = (size_t)(blockIdx.x * 16 + row);

    const float4 a = *reinterpret_cast<const float4*>(&C[grow * HH + c0]);
    const float4 b4 = *reinterpret_cast<const float4*>(&bias[c0]);
    float v[4] = { fmaxf(a.x + b4.x, 0.f), fmaxf(a.y + b4.y, 0.f),
                   fmaxf(a.z + b4.z, 0.f), fmaxf(a.w + b4.w, 0.f) };
    float s = 0.f, ss = 0.f;
#pragma unroll
    for (int j = 0; j < 4; ++j) { s += v[j]; ss += v[j] * v[j]; }
#pragma unroll
    for (int m = 1; m < 16; m <<= 1) {
        s  += __shfl_xor(s,  m, 64);
        ss += __shfl_xor(ss, m, 64);
    }
    const float mean = s * (1.f / 64.f);
    const float var  = fmaxf(ss * (1.f / 64.f) - mean * mean, 0.f);
    const float inv  = rsqrtf(var + LN_EPS);
    const float4 g4  = *reinterpret_cast<const float4*>(&gamma[c0]);
    const float4 be4 = *reinterpret_cast<const float4*>(&beta[c0]);
    float4 o;
    o.x = (v[0] - mean) * inv * g4.x + be4.x;
    o.y = (v[1] - mean) * inv * g4.y + be4.y;
    o.z = (v[2] - mean) * inv * g4.z + be4.z;
    o.w = (v[3] - mean) * inv * g4.w + be4.w;
    if (resid) {
        const float4 r4 = *reinterpret_cast<const float4*>(&resid[grow * HH + c0]);
        o.x += r4.x; o.y += r4.y; o.z += r4.z; o.w += r4.w;
    }
    *reinterpret_cast<float4*>(&out[grow * HH + c0]) = o;
}

// ---------------------------------------------------------------------------
// K3: Zt1 = (h0 @ W1)^T  (bf16 [64][8192]); LDS-staged, coalesced. grid 128 x 256
__global__ __launch_bounds__(256)
void k3_hw1(const float* __restrict__ h0,
            const float* __restrict__ W1,
            __hip_bfloat16* __restrict__ Zt1) {
    __shared__ float Hs[64][65];   // +1 pad
    __shared__ float Ws[64][64];
    const int t  = threadIdx.x;
    const int i0 = blockIdx.x * 64;
#pragma unroll
    for (int p = 0; p < 4; ++p) {   // stage 64x64 h0 tile and 64x64 W1, coalesced
        const int idx = p * 256 + t;
        const int r = idx >> 4, c = (idx & 15) * 4;
        const float4 v = *reinterpret_cast<const float4*>(&h0[(size_t)(i0 + r) * HH + c]);
        Hs[r][c + 0] = v.x; Hs[r][c + 1] = v.y; Hs[r][c + 2] = v.z; Hs[r][c + 3] = v.w;
        const float4 w = *reinterpret_cast<const float4*>(&W1[(size_t)r * HH + c]);
        Ws[r][c + 0] = w.x; Ws[r][c + 1] = w.y; Ws[r][c + 2] = w.z; Ws[r][c + 3] = w.w;
    }
    __syncthreads();
    const int i  = t & 63;
    const int n0 = (t >> 6) * 16;
    float s[16];
#pragma unroll
    for (int j = 0; j < 16; ++j) s[j] = 0.f;
#pragma unroll
    for (int m = 0; m < HH; ++m) {
        const float hv = Hs[i][m];
        const float4* wrow = reinterpret_cast<const float4*>(&Ws[m][n0]);
        const float4 w0 = wrow[0], w1 = wrow[1], w2 = wrow[2], w3 = wrow[3];
        s[0]  += hv * w0.x; s[1]  += hv * w0.y; s[2]  += hv * w0.z; s[3]  += hv * w0.w;
        s[4]  += hv * w1.x; s[5]  += hv * w1.y; s[6]  += hv * w1.z; s[7]  += hv * w1.w;
        s[8]  += hv * w2.x; s[9]  += hv * w2.y; s[10] += hv * w2.z; s[11] += hv * w2.w;
        s[12] += hv * w3.x; s[13] += hv * w3.y; s[14] += hv * w3.z; s[15] += hv * w3.w;
    }
#pragma unroll
    for (int j = 0; j < 16; ++j)
        Zt1[(size_t)(n0 + j) * NN + i0 + i] = __float2bfloat16(s[j]);
}

// ---------------------------------------------------------------------------
// K5: feat = h@Wf + bf ; attn = sigmoid(h@Wa + ba) ; g[I[i]] += feat*attn
// + fused barycentre accumulation. 4 nodes per block (one wave each). grid 2048
__global__ __launch_bounds__(256)
void k5_pool(const float* __restrict__ h,
             const float* __restrict__ Wf, const float* __restrict__ bfv,
             const float* __restrict__ Wa, const float* __restrict__ bav,
             const int* __restrict__ I,
             const float* __restrict__ X,
             const float* __restrict__ zarr,
             const float* __restrict__ zmax,
             float* __restrict__ g,
             float* __restrict__ zsum,
             float* __restrict__ baryn) {
    __shared__ float hrow[4][64];
    const int w = threadIdx.x >> 6, l = threadIdx.x & 63;
    const int node = blockIdx.x * 4 + w;
    hrow[w][l] = h[(size_t)node * HH + l];
    __syncthreads();
    float sf = bfv[l], sa = bav[l];
#pragma unroll 8
    for (int m = 0; m < HH; ++m) {
        const float hv = hrow[w][m];
        sf += hv * Wf[m * HH + l];
        sa += hv * Wa[m * HH + l];
    }
    const float attn = 1.f / (1.f + expf(-sa));
    const int seg = I[node];
    atomicAdd(&g[(size_t)seg * HH + l], sf * attn);

    if (l < 4) {
        const float ze = expf(zarr[node] - zmax[seg]);
        if (l == 0) atomicAdd(&zsum[seg], ze);
        else        atomicAdd(&baryn[seg * 3 + (l - 1)], ze * X[(size_t)node * FF + 12 + l]);
    }
}

// ---------------------------------------------------------------------------
// K7: out[gi] = concat(g[gi], baryn[gi]/zsum[gi]) @ Wout + bout
// one wave per graph; grid 64 x 256. Output fp32.
__global__ __launch_bounds__(256)
void k7_out(const float* __restrict__ g,
            const float* __restrict__ zsum,
            const float* __restrict__ baryn,
            const float* __restrict__ Wout,
            const float* __restrict__ bout,
            float* __restrict__ out) {
    const int w = threadIdx.x >> 6, lane = threadIdx.x & 63;
    const int gi = blockIdx.x * 4 + w;
    const float vg = g[(size_t)gi * HH + lane];
    const float zs = zsum[gi];
    const float invz = (zs > 0.f) ? (1.f / zs) : 0.f;
    const float extra = (lane < 3) ? baryn[gi * 3 + lane] * invz : 0.f;
#pragma unroll
    for (int d = 0; d < 3; ++d) {
        float p = vg * Wout[lane * 3 + d];
        if (lane < 3) p += extra * Wout[(64 + lane) * 3 + d];
#pragma unroll
        for (int m = 1; m < 64; m <<= 1) p += __shfl_xor(p, m, 64);
        if (lane == 0) out[gi * 3 + d] = p + bout[d];
    }
}

// ---------------------------------------------------------------------------
extern "C" void kernel_launch(void* const* d_in, const int* in_sizes, int n_in,
                              void* d_out, int out_size, void* d_ws, size_t ws_size,
                              hipStream_t stream) {
    const float* X   = (const float*)d_in[0];
    const float* A   = (const float*)d_in[1];
    const int*   I   = (const int*)d_in[2];
    const float* W0  = (const float*)d_in[3];
    const float* b0  = (const float*)d_in[4];
    const float* g0  = (const float*)d_in[5];
    const float* be0 = (const float*)d_in[6];
    const float* W1  = (const float*)d_in[7];
    const float* b1  = (const float*)d_in[8];
    const float* g1  = (const float*)d_in[9];
    const float* be1 = (const float*)d_in[10];
    const float* Wf  = (const float*)d_in[11];
    const float* bfv = (const float*)d_in[12];
    const float* Wa  = (const float*)d_in[13];
    const float* bav = (const float*)d_in[14];
    const float* Wo  = (const float*)d_in[15];
    const float* bo  = (const float*)d_in[16];

    char* ws = (char*)d_ws;
    // [C 2MiB][Zt0 1MiB][Zt1 1MiB][h0 2MiB][h 2MiB][zarr 32KiB][acc ~70KB]
    float* C    = (float*)ws;
    __hip_bfloat16* Zt0 = (__hip_bfloat16*)(ws + (2u << 20));
    __hip_bfloat16* Zt1 = (__hip_bfloat16*)(ws + (3u << 20));
    float* h0   = (float*)(ws + (4u << 20));
    float* h    = (float*)(ws + (6u << 20));
    float* zarr = (float*)(ws + (8u << 20));
    float* acc  = (float*)(ws + (8u << 20) + (64u << 10));
    float* g     = acc;                  // 256*64
    float* zmax  = acc + GG * HH;        // 256 (uint bits of float, z>=0)
    float* zsum  = zmax + GG;            // 256
    float* baryn = zsum + GG;            // 256*3
    const size_t memset_bytes = (size_t)(GG * HH + GG + GG + GG * 3) * sizeof(float);

    hipMemsetAsync(acc, 0, memset_bytes, stream);   // 70 KB only

    k1_xw0<<<128, 256, 0, stream>>>(X, W0, I, Zt0, zarr, (unsigned int*)zmax);
    k_gemm_lds<<<512, 256, 0, stream>>>(A, Zt0, C);
    k_ln<<<512, 256, 0, stream>>>(C, b0, g0, be0, nullptr, h0);
    k3_hw1<<<128, 256, 0, stream>>>(h0, W1, Zt1);
    k_gemm_lds<<<512, 256, 0, stream>>>(A, Zt1, C);
    k_ln<<<512, 256, 0, stream>>>(C, b1, g1, be1, h0, h);
    k5_pool<<<2048, 256, 0, stream>>>(h, Wf, bfv, Wa, bav, I, X, zarr, zmax, g, zsum, baryn);
    k7_out<<<64, 256, 0, stream>>>(g, zsum, baryn, Wo, bo, (float*)d_out);
}

// Round 4
// 561.852 us; speedup vs baseline: 1.2174x; 1.2174x over previous
//
#include <hip/hip_runtime.h>
#include <hip/hip_bf16.h>
#include <math.h>

// Problem constants (fixed by the reference)
#define NN 8192     // nodes
#define FF 16       // node features
#define HH 64       // hidden
#define GG 256      // graphs
#define LN_EPS 1e-3f
#define BK 1024              // k-slice per LDS stage (elements)
#define NST (NN / BK)        // 8 stages

typedef __bf16 bf16x8 __attribute__((ext_vector_type(8)));
typedef float  floatx4 __attribute__((ext_vector_type(4)));

// ---------------------------------------------------------------------------
// K1: Zt0 = (X @ W0)^T  (bf16, [64][8192]); LDS-staged, coalesced.
// Also z = log1p(relu(X[:,0])), segment-max of z via uint atomicMax (z >= 0).
// grid 128 x 256 (64 nodes per block)
__global__ __launch_bounds__(256)
void k1_xw0(const float* __restrict__ X,
            const float* __restrict__ W0,
            const int* __restrict__ I,
            __hip_bfloat16* __restrict__ Zt0,
            float* __restrict__ zarr,
            unsigned int* __restrict__ zmax_bits) {
    __shared__ float Xs[64][17];   // +1 pad
    __shared__ float W0s[16][64];
    const int t  = threadIdx.x;
    const int i0 = blockIdx.x * 64;
    {   // stage X tile (64x16) -- one float4 per thread, coalesced
        const int r = t >> 2, c = (t & 3) * 4;
        const float4 v = *reinterpret_cast<const float4*>(&X[(size_t)(i0 + r) * FF + c]);
        Xs[r][c + 0] = v.x; Xs[r][c + 1] = v.y; Xs[r][c + 2] = v.z; Xs[r][c + 3] = v.w;
        const float4 w = *reinterpret_cast<const float4*>(&W0[t * 4]);
        const int wr = t >> 4, wc = (t & 15) * 4;
        W0s[wr][wc + 0] = w.x; W0s[wr][wc + 1] = w.y; W0s[wr][wc + 2] = w.z; W0s[wr][wc + 3] = w.w;
    }
    __syncthreads();
    const int i  = t & 63;          // node within tile
    const int n0 = (t >> 6) * 16;   // 16 output cols per thread
    float s[16];
#pragma unroll
    for (int j = 0; j < 16; ++j) s[j] = 0.f;
#pragma unroll
    for (int m = 0; m < FF; ++m) {
        const float hv = Xs[i][m];
        const float4* wrow = reinterpret_cast<const float4*>(&W0s[m][n0]);
        const float4 w0 = wrow[0], w1 = wrow[1], w2 = wrow[2], w3 = wrow[3];
        s[0]  += hv * w0.x; s[1]  += hv * w0.y; s[2]  += hv * w0.z; s[3]  += hv * w0.w;
        s[4]  += hv * w1.x; s[5]  += hv * w1.y; s[6]  += hv * w1.z; s[7]  += hv * w1.w;
        s[8]  += hv * w2.x; s[9]  += hv * w2.y; s[10] += hv * w2.z; s[11] += hv * w2.w;
        s[12] += hv * w3.x; s[13] += hv * w3.y; s[14] += hv * w3.z; s[15] += hv * w3.w;
    }
#pragma unroll
    for (int j = 0; j < 16; ++j)
        Zt0[(size_t)(n0 + j) * NN + i0 + i] = __float2bfloat16(s[j]);  // 128B coalesced

    if (t < 64) {
        const float z = log1pf(fmaxf(Xs[t][0], 0.f));
        zarr[i0 + t] = z;
        atomicMax(&zmax_bits[I[i0 + t]], __float_as_uint(z));
    }
}

// ---------------------------------------------------------------------------
// Streaming GEMM + fused LN epilogue.
// out = LayerNorm(relu(A @ Z + bias)) * gamma + beta (+ resid)
// grid 512 x 256 (4 waves); block = 16 rows, full-K accumulate.
// A staged in LDS as BF16 double-buffer [2][16][1024] (32 KB each):
//   - staging loads are 4 KB *sequential runs per row* (fp32 source) -> DRAM
//     page-friendly (round-3's 1 KB runs measured ~20% HBM efficiency);
//   - bf16 LDS halves LDS bytes and removes per-MFMA f32->bf16 cvt chains.
// Reg-split staging (T14): issue 16 float4 loads early, cvt+ds_write late.
// XOR swizzle on byte addr: cbyte ^ ((row&7)<<4), same on write and read.
// Wave w computes cols w*16..+15 for all 16 rows.
__global__ __launch_bounds__(256)
void k_gemm_ln(const float* __restrict__ A,
               const __hip_bfloat16* __restrict__ Zt,
               const float* __restrict__ bias,
               const float* __restrict__ gamma,
               const float* __restrict__ beta,
               const float* __restrict__ resid,   // nullptr for layer 0
               float* __restrict__ out) {
    __shared__ __hip_bfloat16 Ab[2][16][BK];   // 64 KB
    __shared__ float CLn[16][68];              // epilogue scratch (+pad)
    const int t    = threadIdx.x;
    const int w    = t >> 6;
    const int lane = t & 63;
    const int l16  = lane & 15;
    const int quad = lane >> 4;
    const int row0 = blockIdx.x * 16;

    // B operand: lane l16 -> Zt col (w*16+l16); quad -> k-octet
    const __hip_bfloat16* bp = Zt + (size_t)(w * 16 + l16) * NN + quad * 8;
    const float* arow = A + (size_t)row0 * NN;

    char* ab0 = reinterpret_cast<char*>(&Ab[0][0][0]);
    char* ab1 = reinterpret_cast<char*>(&Ab[1][0][0]);

    floatx4 acc = {0.f, 0.f, 0.f, 0.f};

    // staging helper data: wave w stages rows w*4..w*4+3; per row 4 chunks of
    // 256 floats; lane covers floats [lane*4, lane*4+4) of each chunk.
    // write granularity: 4 bf16 = 8 B (ushort4), swizzled.
#define STAGE_LOAD(dst, s_)                                                      \
    {                                                                            \
        _Pragma("unroll")                                                        \
        for (int r4 = 0; r4 < 4; ++r4)                                           \
            _Pragma("unroll")                                                    \
            for (int c = 0; c < 4; ++c)                                          \
                dst[r4 * 4 + c] = *reinterpret_cast<const float4*>(              \
                    arow + (size_t)(w * 4 + r4) * NN + (size_t)(s_) * BK +       \
                    c * 256 + lane * 4);                                         \
    }
#define STAGE_WRITE(src, abase)                                                  \
    {                                                                            \
        _Pragma("unroll")                                                        \
        for (int r4 = 0; r4 < 4; ++r4) {                                         \
            const int row = w * 4 + r4;                                          \
            const int rsw = (row & 7) << 4;                                      \
            _Pragma("unroll")                                                    \
            for (int c = 0; c < 4; ++c) {                                        \
                const float4 v = src[r4 * 4 + c];                                \
                __hip_bfloat16 h0_ = __float2bfloat16(v.x);                      \
                __hip_bfloat16 h1_ = __float2bfloat16(v.y);                      \
                __hip_bfloat16 h2_ = __float2bfloat16(v.z);                      \
                __hip_bfloat16 h3_ = __float2bfloat16(v.w);                      \
                ushort4 u;                                                       \
                u.x = *reinterpret_cast<unsigned short*>(&h0_);                  \
                u.y = *reinterpret_cast<unsigned short*>(&h1_);                  \
                u.z = *reinterpret_cast<unsigned short*>(&h2_);                  \
                u.w = *reinterpret_cast<unsigned short*>(&h3_);                  \
                const int cbyte = (c * 256 + lane * 4) * 2;                      \
                *reinterpret_cast<ushort4*>(                                     \
                    abase + row * (BK * 2) + (cbyte ^ rsw)) = u;                 \
            }                                                                    \
        }                                                                        \
    }

    // prologue: stage 0 into buffer 0
    {
        float4 st[16];
        STAGE_LOAD(st, 0)
        STAGE_WRITE(st, ab0)
    }
    __syncthreads();

    const int rswz = (l16 & 7) << 4;   // read-side XOR (bytes)
    int cur = 0;
    for (int s = 0; s < NST; ++s) {
        float4 nx[16];
        const bool pf = (s + 1 < NST);
        if (pf) STAGE_LOAD(nx, s + 1)          // issue early: hides under MFMA
        const char* ab = cur ? ab1 : ab0;
        const char* arow_l = ab + l16 * (BK * 2);
#pragma unroll 4
        for (int kk = 0; kk < BK / 32; ++kk) {
            const bf16x8 af = *reinterpret_cast<const bf16x8*>(
                arow_l + ((kk * 64 + quad * 16) ^ rswz));
            const bf16x8 b = *reinterpret_cast<const bf16x8*>(
                bp + (size_t)s * BK + kk * 32);
            acc = __builtin_amdgcn_mfma_f32_16x16x32_bf16(af, b, acc, 0, 0, 0);
        }
        if (pf) STAGE_WRITE(nx, (cur ? ab0 : ab1))
        __syncthreads();
        cur ^= 1;
    }
#undef STAGE_LOAD
#undef STAGE_WRITE

    // ---- fused epilogue: cross-wave gather + LayerNorm on the 16 rows ----
    // C/D layout: m = quad*4 + reg, n = l16 (HW-verified m89/m91)
#pragma unroll
    for (int r = 0; r < 4; ++r)
        CLn[quad * 4 + r][w * 16 + l16] = acc[r];
    __syncthreads();

    const int row = t >> 4;
    const int c0  = (t & 15) * 4;
    const size_t grow = (size_t)(row0 + row);
    const float4 a4 = *reinterpret_cast<const float4*>(&CLn[row][c0]);
    const float4 b4 = *reinterpret_cast<const float4*>(&bias[c0]);
    float v[4] = { fmaxf(a4.x + b4.x, 0.f), fmaxf(a4.y + b4.y, 0.f),
                   fmaxf(a4.z + b4.z, 0.f), fmaxf(a4.w + b4.w, 0.f) };
    float s = 0.f, ss = 0.f;
#pragma unroll
    for (int j = 0; j < 4; ++j) { s += v[j]; ss += v[j] * v[j]; }
#pragma unroll
    for (int m = 1; m < 16; m <<= 1) {
        s  += __shfl_xor(s,  m, 64);
        ss += __shfl_xor(ss, m, 64);
    }
    const float mean = s * (1.f / 64.f);
    const float var  = fmaxf(ss * (1.f / 64.f) - mean * mean, 0.f);
    const float inv  = rsqrtf(var + LN_EPS);
    const float4 g4  = *reinterpret_cast<const float4*>(&gamma[c0]);
    const float4 be4 = *reinterpret_cast<const float4*>(&beta[c0]);
    float4 o;
    o.x = (v[0] - mean) * inv * g4.x + be4.x;
    o.y = (v[1] - mean) * inv * g4.y + be4.y;
    o.z = (v[2] - mean) * inv * g4.z + be4.z;
    o.w = (v[3] - mean) * inv * g4.w + be4.w;
    if (resid) {
        const float4 r4 = *reinterpret_cast<const float4*>(&resid[grow * HH + c0]);
        o.x += r4.x; o.y += r4.y; o.z += r4.z; o.w += r4.w;
    }
    *reinterpret_cast<float4*>(&out[grow * HH + c0]) = o;
}

// ---------------------------------------------------------------------------
// K3: Zt1 = (h0 @ W1)^T  (bf16 [64][8192]); LDS-staged, coalesced. grid 128 x 256
__global__ __launch_bounds__(256)
void k3_hw1(const float* __restrict__ h0,
            const float* __restrict__ W1,
            __hip_bfloat16* __restrict__ Zt1) {
    __shared__ float Hs[64][65];   // +1 pad
    __shared__ float Ws[64][64];
    const int t  = threadIdx.x;
    const int i0 = blockIdx.x * 64;
#pragma unroll
    for (int p = 0; p < 4; ++p) {
        const int idx = p * 256 + t;
        const int r = idx >> 4, c = (idx & 15) * 4;
        const float4 v = *reinterpret_cast<const float4*>(&h0[(size_t)(i0 + r) * HH + c]);
        Hs[r][c + 0] = v.x; Hs[r][c + 1] = v.y; Hs[r][c + 2] = v.z; Hs[r][c + 3] = v.w;
        const float4 w = *reinterpret_cast<const float4*>(&W1[(size_t)r * HH + c]);
        Ws[r][c + 0] = w.x; Ws[r][c + 1] = w.y; Ws[r][c + 2] = w.z; Ws[r][c + 3] = w.w;
    }
    __syncthreads();
    const int i  = t & 63;
    const int n0 = (t >> 6) * 16;
    float s[16];
#pragma unroll
    for (int j = 0; j < 16; ++j) s[j] = 0.f;
#pragma unroll
    for (int m = 0; m < HH; ++m) {
        const float hv = Hs[i][m];
        const float4* wrow = reinterpret_cast<const float4*>(&Ws[m][n0]);
        const float4 w0 = wrow[0], w1 = wrow[1], w2 = wrow[2], w3 = wrow[3];
        s[0]  += hv * w0.x; s[1]  += hv * w0.y; s[2]  += hv * w0.z; s[3]  += hv * w0.w;
        s[4]  += hv * w1.x; s[5]  += hv * w1.y; s[6]  += hv * w1.z; s[7]  += hv * w1.w;
        s[8]  += hv * w2.x; s[9]  += hv * w2.y; s[10] += hv * w2.z; s[11] += hv * w2.w;
        s[12] += hv * w3.x; s[13] += hv * w3.y; s[14] += hv * w3.z; s[15] += hv * w3.w;
    }
#pragma unroll
    for (int j = 0; j < 16; ++j)
        Zt1[(size_t)(n0 + j) * NN + i0 + i] = __float2bfloat16(s[j]);
}

// ---------------------------------------------------------------------------
// K5: feat = h@Wf + bf ; attn = sigmoid(h@Wa + ba) ; g[I[i]] += feat*attn
// + fused barycentre accumulation. 4 nodes per block (one wave each). grid 2048
__global__ __launch_bounds__(256)
void k5_pool(const float* __restrict__ h,
             const float* __restrict__ Wf, const float* __restrict__ bfv,
             const float* __restrict__ Wa, const float* __restrict__ bav,
             const int* __restrict__ I,
             const float* __restrict__ X,
             const float* __restrict__ zarr,
             const float* __restrict__ zmax,
             float* __restrict__ g,
             float* __restrict__ zsum,
             float* __restrict__ baryn) {
    __shared__ float hrow[4][64];
    const int w = threadIdx.x >> 6, l = threadIdx.x & 63;
    const int node = blockIdx.x * 4 + w;
    hrow[w][l] = h[(size_t)node * HH + l];
    __syncthreads();
    float sf = bfv[l], sa = bav[l];
#pragma unroll 8
    for (int m = 0; m < HH; ++m) {
        const float hv = hrow[w][m];
        sf += hv * Wf[m * HH + l];
        sa += hv * Wa[m * HH + l];
    }
    const float attn = 1.f / (1.f + expf(-sa));
    const int seg = I[node];
    atomicAdd(&g[(size_t)seg * HH + l], sf * attn);

    if (l < 4) {
        const float ze = expf(zarr[node] - zmax[seg]);
        if (l == 0) atomicAdd(&zsum[seg], ze);
        else        atomicAdd(&baryn[seg * 3 + (l - 1)], ze * X[(size_t)node * FF + 12 + l]);
    }
}

// ---------------------------------------------------------------------------
// K7: out[gi] = concat(g[gi], baryn[gi]/zsum[gi]) @ Wout + bout
// one wave per graph; grid 64 x 256. Output fp32.
__global__ __launch_bounds__(256)
void k7_out(const float* __restrict__ g,
            const float* __restrict__ zsum,
            const float* __restrict__ baryn,
            const float* __restrict__ Wout,
            const float* __restrict__ bout,
            float* __restrict__ out) {
    const int w = threadIdx.x >> 6, lane = threadIdx.x & 63;
    const int gi = blockIdx.x * 4 + w;
    const float vg = g[(size_t)gi * HH + lane];
    const float zs = zsum[gi];
    const float invz = (zs > 0.f) ? (1.f / zs) : 0.f;
    const float extra = (lane < 3) ? baryn[gi * 3 + lane] * invz : 0.f;
#pragma unroll
    for (int d = 0; d < 3; ++d) {
        float p = vg * Wout[lane * 3 + d];
        if (lane < 3) p += extra * Wout[(64 + lane) * 3 + d];
#pragma unroll
        for (int m = 1; m < 64; m <<= 1) p += __shfl_xor(p, m, 64);
        if (lane == 0) out[gi * 3 + d] = p + bout[d];
    }
}

// ---------------------------------------------------------------------------
extern "C" void kernel_launch(void* const* d_in, const int* in_sizes, int n_in,
                              void* d_out, int out_size, void* d_ws, size_t ws_size,
                              hipStream_t stream) {
    const float* X   = (const float*)d_in[0];
    const float* A   = (const float*)d_in[1];
    const int*   I   = (const int*)d_in[2];
    const float* W0  = (const float*)d_in[3];
    const float* b0  = (const float*)d_in[4];
    const float* g0  = (const float*)d_in[5];
    const float* be0 = (const float*)d_in[6];
    const float* W1  = (const float*)d_in[7];
    const float* b1  = (const float*)d_in[8];
    const float* g1  = (const float*)d_in[9];
    const float* be1 = (const float*)d_in[10];
    const float* Wf  = (const float*)d_in[11];
    const float* bfv = (const float*)d_in[12];
    const float* Wa  = (const float*)d_in[13];
    const float* bav = (const float*)d_in[14];
    const float* Wo  = (const float*)d_in[15];
    const float* bo  = (const float*)d_in[16];

    char* ws = (char*)d_ws;
    // [Zt0 1MiB][Zt1 1MiB][h0 2MiB][h 2MiB][zarr 32KiB][acc ~70KB]
    __hip_bfloat16* Zt0 = (__hip_bfloat16*)(ws);
    __hip_bfloat16* Zt1 = (__hip_bfloat16*)(ws + (1u << 20));
    float* h0   = (float*)(ws + (2u << 20));
    float* h    = (float*)(ws + (4u << 20));
    float* zarr = (float*)(ws + (6u << 20));
    float* acc  = (float*)(ws + (6u << 20) + (64u << 10));
    float* g     = acc;                  // 256*64
    float* zmax  = acc + GG * HH;        // 256 (uint bits of float, z>=0)
    float* zsum  = zmax + GG;            // 256
    float* baryn = zsum + GG;            // 256*3
    const size_t memset_bytes = (size_t)(GG * HH + GG + GG + GG * 3) * sizeof(float);

    hipMemsetAsync(acc, 0, memset_bytes, stream);   // 70 KB only

    k1_xw0<<<128, 256, 0, stream>>>(X, W0, I, Zt0, zarr, (unsigned int*)zmax);
    k_gemm_ln<<<512, 256, 0, stream>>>(A, Zt0, b0, g0, be0, nullptr, h0);
    k3_hw1<<<128, 256, 0, stream>>>(h0, W1, Zt1);
    k_gemm_ln<<<512, 256, 0, stream>>>(A, Zt1, b1, g1, be1, h0, h);
    k5_pool<<<2048, 256, 0, stream>>>(h, Wf, bfv, Wa, bav, I, X, zarr, zmax, g, zsum, baryn);
    k7_out<<<64, 256, 0, stream>>>(g, zsum, baryn, Wo, bo, (float*)d_out);
}